// Round 1
// baseline (2020.368 us; speedup 1.0000x reference)
//
#include <hip/hip_runtime.h>
#include <math.h>

// Problem constants (fixed by the reference)
constexpr int BSZ      = 64;
constexpr int SEQL     = 576;
constexpr int FTIN     = 768;
constexpr int HID      = 512;
constexpr int NNODE    = SEQL + 1;          // 577
constexpr int NUM_NODES= BSZ * NNODE;        // 36928
constexpr int MROWS    = BSZ * SEQL;         // 36864

__device__ __forceinline__ float gelu_f(float x) {
    // jax.nn.gelu default approximate=True (tanh form)
    float x3 = x * x * x;
    return 0.5f * x * (1.0f + tanhf(0.7978845608028654f * (x + 0.044715f * x3)));
}
__device__ __forceinline__ float lrelu(float x) {
    return x > 0.0f ? x : 0.2f * x;
}

// ---------------------------------------------------------------------------
// Generic fp32 GEMM: C[M x 512] = act(A[M x K] @ B[K x 512] + bias)
// 128x128 tile, 256 threads, 8x8 per thread. Optional GELU, optional row remap
// (for writing GEMM2 output into the concat'd x buffer: out_r = r + r/SEQ + 1).
// ---------------------------------------------------------------------------
template<bool GELU, bool REMAP>
__global__ __launch_bounds__(256) void gemm_k(
    const float* __restrict__ A, const float* __restrict__ B,
    const float* __restrict__ bias, float* __restrict__ C,
    int M, int K)
{
    __shared__ float As[16][128];   // transposed: As[k][m]
    __shared__ float Bs[16][132];   // padded row stride (132 = 4*33) -> 2-way max

    const int tid  = threadIdx.x;
    const int row0 = blockIdx.x * 128;
    const int col0 = blockIdx.y * 128;

    float acc[8][8];
#pragma unroll
    for (int i = 0; i < 8; i++)
#pragma unroll
        for (int j = 0; j < 8; j++) acc[i][j] = 0.0f;

    const int ar = tid >> 1;          // 0..127  (A tile row)
    const int ak = (tid & 1) * 8;     // 0 or 8  (A tile k-offset)
    const int bk = tid >> 4;          // 0..15   (B tile k-row)
    const int bc = (tid & 15) * 8;    // 0..120  (B tile col)
    const int ty = tid >> 4;          // 0..15
    const int tx = tid & 15;          // 0..15

    for (int k0 = 0; k0 < K; k0 += 16) {
        float4 a0, a1;
        const int arow = row0 + ar;
        if (arow < M) {
            const float* ap = A + (size_t)arow * K + k0 + ak;
            a0 = *(const float4*)ap;
            a1 = *(const float4*)(ap + 4);
        } else {
            a0 = make_float4(0.f, 0.f, 0.f, 0.f);
            a1 = make_float4(0.f, 0.f, 0.f, 0.f);
        }
        const float* bp = B + (size_t)(k0 + bk) * 512 + col0 + bc;
        float4 b0 = *(const float4*)bp;
        float4 b1 = *(const float4*)(bp + 4);

        __syncthreads();   // protect previous iteration's LDS reads
        As[ak + 0][ar] = a0.x; As[ak + 1][ar] = a0.y;
        As[ak + 2][ar] = a0.z; As[ak + 3][ar] = a0.w;
        As[ak + 4][ar] = a1.x; As[ak + 5][ar] = a1.y;
        As[ak + 6][ar] = a1.z; As[ak + 7][ar] = a1.w;
        *(float4*)&Bs[bk][bc]     = b0;
        *(float4*)&Bs[bk][bc + 4] = b1;
        __syncthreads();

#pragma unroll
        for (int kk = 0; kk < 16; kk++) {
            float av[8], bv[8];
            *(float4*)(av)     = *(const float4*)&As[kk][ty * 8];
            *(float4*)(av + 4) = *(const float4*)&As[kk][ty * 8 + 4];
            *(float4*)(bv)     = *(const float4*)&Bs[kk][tx * 4];
            *(float4*)(bv + 4) = *(const float4*)&Bs[kk][64 + tx * 4];
#pragma unroll
            for (int i = 0; i < 8; i++)
#pragma unroll
                for (int j = 0; j < 8; j++)
                    acc[i][j] = fmaf(av[i], bv[j], acc[i][j]);
        }
    }

#pragma unroll
    for (int i = 0; i < 8; i++) {
        const int r = row0 + ty * 8 + i;
        if (r < M) {
            const int out_r = REMAP ? (r + r / SEQL + 1) : r;
            float* crow = C + (size_t)out_r * 512;
#pragma unroll
            for (int half = 0; half < 2; half++) {
                const int c = col0 + half * 64 + tx * 4;
                float4 v;
                v.x = acc[i][half * 4 + 0] + bias[c + 0];
                v.y = acc[i][half * 4 + 1] + bias[c + 1];
                v.z = acc[i][half * 4 + 2] + bias[c + 2];
                v.w = acc[i][half * 4 + 3] + bias[c + 3];
                if (GELU) {
                    v.x = gelu_f(v.x); v.y = gelu_f(v.y);
                    v.z = gelu_f(v.z); v.w = gelu_f(v.w);
                }
                *(float4*)(crow + c) = v;
            }
        }
    }
}

// ---------------------------------------------------------------------------
// x[b*577 + 0] = pooled[b]
// ---------------------------------------------------------------------------
__global__ void build_x_pooled(const float* __restrict__ pooled,
                               float* __restrict__ x)
{
    const int b = blockIdx.x;
    const int t = threadIdx.x;   // 512 threads
    x[(size_t)(b * NNODE) * HID + t] = pooled[b * HID + t];
}

// ---------------------------------------------------------------------------
// GAT combine for dst nodes j >= 1 : softmax over {src=0, src=j} edges.
// One block (256 thr) per node; thread t owns channels 2t, 2t+1.
// For HEADS=4 each wave == one head; for HEADS=1 the 4 waves combine via LDS.
// ---------------------------------------------------------------------------
template<int HEADS, bool GELU>
__global__ __launch_bounds__(256) void gat_edge_k(
    const float* __restrict__ xl, const float* __restrict__ xr,
    const float* __restrict__ att, const float* __restrict__ bias,
    float* __restrict__ out)
{
    const int b = blockIdx.x / SEQL;
    const int j = blockIdx.x % SEQL;
    const size_t row0 = (size_t)(b * NNODE) * HID;           // node 0 of batch
    const size_t rowj = (size_t)(b * NNODE + 1 + j) * HID;   // node j
    const int t = threadIdx.x;
    const int c = 2 * t;

    const float2 xl0  = *(const float2*)(xl + row0 + c);
    const float2 xljv = *(const float2*)(xl + rowj + c);
    const float2 xrjv = *(const float2*)(xr + rowj + c);
    const float2 attc = *(const float2*)(att + c);

    float e0 = attc.x * lrelu(xl0.x + xrjv.x) + attc.y * lrelu(xl0.y + xrjv.y);
    float e1 = attc.x * lrelu(xljv.x + xrjv.x) + attc.y * lrelu(xljv.y + xrjv.y);

#pragma unroll
    for (int off = 32; off; off >>= 1) {
        e0 += __shfl_down(e0, off, 64);
        e1 += __shfl_down(e1, off, 64);
    }
    __shared__ float s0[4], s1[4];
    const int w = t >> 6, lane = t & 63;
    if (lane == 0) { s0[w] = e0; s1[w] = e1; }
    __syncthreads();

    float E0, E1;
    if (HEADS == 4) { E0 = s0[w]; E1 = s1[w]; }
    else            { E0 = s0[0] + s0[1] + s0[2] + s0[3];
                      E1 = s1[0] + s1[1] + s1[2] + s1[3]; }

    const float m  = fmaxf(E0, E1);
    const float p0 = expf(E0 - m);
    const float p1 = expf(E1 - m);
    const float inv = 1.0f / (p0 + p1 + 1e-16f);
    const float a0 = p0 * inv, a1 = p1 * inv;

    float2 o;
    o.x = a0 * xl0.x + a1 * xljv.x + bias[c + 0];
    o.y = a0 * xl0.y + a1 * xljv.y + bias[c + 1];
    if (GELU) { o.x = gelu_f(o.x); o.y = gelu_f(o.y); }
    *(float2*)(out + rowj + c) = o;
}

// ---------------------------------------------------------------------------
// GAT combine for dst node 0: softmax over all 577 sources of the batch.
// One block (256 thr) per (batch, head). Two-pass with e[] staged in LDS.
// ---------------------------------------------------------------------------
template<int HEADS, bool GELU>
__global__ __launch_bounds__(256) void gat_node0_k(
    const float* __restrict__ xl, const float* __restrict__ xr,
    const float* __restrict__ att, const float* __restrict__ bias,
    float* __restrict__ out)
{
    constexpr int CH = HID / HEADS;
    const int b = blockIdx.x;
    const int h = blockIdx.y;
    const int t = threadIdx.x;
    const size_t base = (size_t)(b * NNODE) * HID;   // node-0 row offset

    __shared__ float xr0s[CH];
    __shared__ float es[NNODE];
    __shared__ float red[256];

    const float* atth = att + h * CH;
    for (int c = t; c < CH; c += 256) xr0s[c] = xr[base + h * CH + c];
    __syncthreads();

    // pass 1: e_s for every source s
    for (int s = t; s < NNODE; s += 256) {
        const float* xls = xl + base + (size_t)s * HID + h * CH;
        float e = 0.0f;
        for (int c = 0; c < CH; c += 4) {
            float4 v = *(const float4*)(xls + c);
            float4 a = *(const float4*)(atth + c);
            e = fmaf(a.x, lrelu(v.x + xr0s[c + 0]), e);
            e = fmaf(a.y, lrelu(v.y + xr0s[c + 1]), e);
            e = fmaf(a.z, lrelu(v.z + xr0s[c + 2]), e);
            e = fmaf(a.w, lrelu(v.w + xr0s[c + 3]), e);
        }
        es[s] = e;
    }
    __syncthreads();

    // max-reduce
    float m = -INFINITY;
    for (int s = t; s < NNODE; s += 256) m = fmaxf(m, es[s]);
    red[t] = m; __syncthreads();
    for (int off = 128; off; off >>= 1) {
        if (t < off) red[t] = fmaxf(red[t], red[t + off]);
        __syncthreads();
    }
    m = red[0];
    __syncthreads();   // everyone has read red[0] before it is overwritten

    // exp + sum-reduce
    float sum = 0.0f;
    for (int s = t; s < NNODE; s += 256) {
        float p = expf(es[s] - m);
        es[s] = p;
        sum += p;
    }
    red[t] = sum; __syncthreads();
    for (int off = 128; off; off >>= 1) {
        if (t < off) red[t] += red[t + off];
        __syncthreads();
    }
    const float invS = 1.0f / (red[0] + 1e-16f);

    // pass 2: out[0][h,:] = sum_s alpha_s * xl[s][h,:]
    for (int c = t; c < CH; c += 256) {
        float acc = 0.0f;
        for (int s = 0; s < NNODE; s++)
            acc = fmaf(es[s], xl[base + (size_t)s * HID + h * CH + c], acc);
        float o = acc * invS + bias[h * CH + c];
        if (GELU) o = gelu_f(o);
        out[base + h * CH + c] = o;
    }
}

// ---------------------------------------------------------------------------
// graph_mean: mean over the 577 nodes of each batch -> d_out[32768 + b*512 + c]
// ---------------------------------------------------------------------------
__global__ __launch_bounds__(256) void mean_k(const float* __restrict__ h2,
                                              float* __restrict__ out)
{
    const int b = blockIdx.x;
    const int c = blockIdx.y * 256 + threadIdx.x;
    const float* p = h2 + (size_t)(b * NNODE) * HID + c;
    float s = 0.0f;
    for (int i = 0; i < NNODE; i++) s += p[(size_t)i * HID];
    out[(size_t)BSZ * HID + b * HID + c] = s * (1.0f / NNODE);
}

// ---------------------------------------------------------------------------
// out = cls @ linw + linb + pooled  -> d_out[b*512 + col]
// ---------------------------------------------------------------------------
__global__ __launch_bounds__(256) void head_k(
    const float* __restrict__ h2, const float* __restrict__ linw,
    const float* __restrict__ linb, const float* __restrict__ pooled,
    float* __restrict__ out)
{
    const int b = blockIdx.x;
    const int col = blockIdx.y * 256 + threadIdx.x;
    __shared__ float cls[HID];
    for (int k = threadIdx.x; k < HID; k += 256)
        cls[k] = h2[(size_t)(b * NNODE) * HID + k];
    __syncthreads();
    float acc = 0.0f;
    for (int k = 0; k < HID; k++)
        acc = fmaf(cls[k], linw[(size_t)k * HID + col], acc);
    out[b * HID + col] = acc + linb[col] + pooled[b * HID + col];
}

// ---------------------------------------------------------------------------
extern "C" void kernel_launch(void* const* d_in, const int* in_sizes, int n_in,
                              void* d_out, int out_size, void* d_ws, size_t ws_size,
                              hipStream_t stream)
{
    const float* hs     = (const float*)d_in[0];
    const float* pooled = (const float*)d_in[1];
    const float* pw1  = (const float*)d_in[2];  const float* pb1   = (const float*)d_in[3];
    const float* pw2  = (const float*)d_in[4];  const float* pb2   = (const float*)d_in[5];
    const float* wl1  = (const float*)d_in[6];  const float* bl1   = (const float*)d_in[7];
    const float* wr1  = (const float*)d_in[8];  const float* br1   = (const float*)d_in[9];
    const float* att1 = (const float*)d_in[10]; const float* bias1 = (const float*)d_in[11];
    const float* wl2  = (const float*)d_in[12]; const float* bl2   = (const float*)d_in[13];
    const float* wr2  = (const float*)d_in[14]; const float* br2   = (const float*)d_in[15];
    const float* att2 = (const float*)d_in[16]; const float* bias2 = (const float*)d_in[17];
    const float* linw = (const float*)d_in[18]; const float* linb  = (const float*)d_in[19];
    float* out = (float*)d_out;

    // workspace: 3 rotating slots of NUM_NODES x 512 f32  (~227 MB total)
    const size_t slot = (size_t)NUM_NODES * HID;
    float* bufA = (float*)d_ws;          // h_tmp -> xr1 -> xr2
    float* bufB = bufA + slot;           // x -> h1 -> h2
    float* bufC = bufB + slot;           // xl1 -> xl2

    const dim3 blk(256);
    const dim3 g1(MROWS / 128, 4);                  // 288 x 4
    const dim3 g2((NUM_NODES + 127) / 128, 4);      // 289 x 4

    // 1) A = gelu(hs @ pw1 + pb1)
    gemm_k<true, false><<<g1, blk, 0, stream>>>(hs, pw1, pb1, bufA, MROWS, FTIN);
    // 2) x (bufB): sequence rows via remap, node-0 rows = pooled
    gemm_k<false, true><<<g1, blk, 0, stream>>>(bufA, pw2, pb2, bufB, MROWS, HID);
    build_x_pooled<<<dim3(BSZ), dim3(512), 0, stream>>>(pooled, bufB);
    // 3) GAT layer 1 projections
    gemm_k<false, false><<<g2, blk, 0, stream>>>(bufB, wl1, bl1, bufC, NUM_NODES, HID);
    gemm_k<false, false><<<g2, blk, 0, stream>>>(bufB, wr1, br1, bufA, NUM_NODES, HID);
    // 4) GAT layer 1 combine (+bias, gelu) -> h1 in bufB
    gat_edge_k<4, true><<<dim3(MROWS), blk, 0, stream>>>(bufC, bufA, att1, bias1, bufB);
    gat_node0_k<4, true><<<dim3(BSZ, 4), blk, 0, stream>>>(bufC, bufA, att1, bias1, bufB);
    // 5) GAT layer 2 projections
    gemm_k<false, false><<<g2, blk, 0, stream>>>(bufB, wl2, bl2, bufC, NUM_NODES, HID);
    gemm_k<false, false><<<g2, blk, 0, stream>>>(bufB, wr2, br2, bufA, NUM_NODES, HID);
    // 6) GAT layer 2 combine (+bias) -> h2 in bufB
    gat_edge_k<1, false><<<dim3(MROWS), blk, 0, stream>>>(bufC, bufA, att2, bias2, bufB);
    gat_node0_k<1, false><<<dim3(BSZ, 1), blk, 0, stream>>>(bufC, bufA, att2, bias2, bufB);
    // 7) outputs
    head_k<<<dim3(BSZ, 2), blk, 0, stream>>>(bufB, linw, linb, pooled, out);
    mean_k<<<dim3(BSZ, 2), blk, 0, stream>>>(bufB, out);
}

// Round 2
// 1083.774 us; speedup vs baseline: 1.8642x; 1.8642x over previous
//
#include <hip/hip_runtime.h>
#include <hip/hip_bf16.h>
#include <math.h>

// Problem constants (fixed by the reference)
constexpr int BSZ       = 64;
constexpr int SEQL      = 576;
constexpr int FTIN      = 768;
constexpr int HID       = 512;
constexpr int NNODE     = SEQL + 1;          // 577
constexpr int NUM_NODES = BSZ * NNODE;       // 36928
constexpr int MROWS     = BSZ * SEQL;        // 36864

using b8 = __attribute__((ext_vector_type(8))) __bf16;
using f4 = __attribute__((ext_vector_type(4))) float;

__device__ __forceinline__ float gelu_f(float x) {
    float x3 = x * x * x;
    return 0.5f * x * (1.0f + tanhf(0.7978845608028654f * (x + 0.044715f * x3)));
}
__device__ __forceinline__ float lrelu(float x) {
    return x > 0.0f ? x : 0.2f * x;
}
__device__ __forceinline__ unsigned short f2bf(float v) {
    __hip_bfloat16 b = __float2bfloat16(v);   // RNE
    return __builtin_bit_cast(unsigned short, b);
}
__device__ __forceinline__ float bf2f(unsigned short u) {
    return __bfloat162float(__builtin_bit_cast(__hip_bfloat16, u));
}
__device__ __forceinline__ void split_bf(float v, unsigned short& h, unsigned short& l) {
    h = f2bf(v);
    l = f2bf(v - bf2f(h));
}
__device__ __forceinline__ void gl16(const void* g, void* l) {
    __builtin_amdgcn_global_load_lds(
        (const __attribute__((address_space(1))) unsigned int*)g,
        (__attribute__((address_space(3))) unsigned int*)l, 16, 0, 0);
}
__device__ __forceinline__ f4 mfma16(b8 a, b8 b, f4 c) {
    return __builtin_amdgcn_mfma_f32_16x16x32_bf16(a, b, c, 0, 0, 0);
}

// ---------------------------------------------------------------------------
// Weight prep: W fp32 [K x N] -> W^T hi/lo bf16 [N x K]
// ---------------------------------------------------------------------------
__global__ __launch_bounds__(256) void transpose_split_k(
    const float* __restrict__ W, unsigned short* __restrict__ Th,
    unsigned short* __restrict__ Tl, int K, int N)
{
    __shared__ float t[64][65];
    const int kb = blockIdx.x * 64, nb = blockIdx.y * 64;
    for (int i = threadIdx.x; i < 64 * 64; i += 256) {
        int r = i >> 6, c = i & 63;
        t[r][c] = W[(size_t)(kb + r) * N + nb + c];
    }
    __syncthreads();
    for (int i = threadIdx.x; i < 64 * 64; i += 256) {
        int r = i >> 6, c = i & 63;          // r: n index, c: k index
        float v = t[c][r];
        unsigned short h, l; split_bf(v, h, l);
        Th[(size_t)(nb + r) * K + kb + c] = h;
        Tl[(size_t)(nb + r) * K + kb + c] = l;
    }
}

// ---------------------------------------------------------------------------
// MFMA GEMM with hi/lo bf16 split inputs (3-product fp32-accurate).
// C[M x 512] = A[M x K] @ B[K x 512] + bias, then per MODE:
//   MODE 0: write fp32
//   MODE 1: gelu, split -> Ch/Cl bf16
//   MODE 2: split -> Ch/Cl bf16 at remapped row (r + r/576 + 1)
// A given as hi/lo bf16 (AF32=false) or raw fp32 (AF32=true, reg-staged split).
// B given pre-transposed+split: BTh/BTl are [512 x K] bf16.
// 128x128 tile, 4 waves, 16x16x32 MFMA, 48 MFMA + 16 ds_read_b128 / K-step.
// ---------------------------------------------------------------------------
template<int MODE, bool AF32>
__global__ __launch_bounds__(256) void bgemm(
    const unsigned short* __restrict__ Ah, const unsigned short* __restrict__ Al,
    const float* __restrict__ Af,
    const unsigned short* __restrict__ BTh, const unsigned short* __restrict__ BTl,
    const float* __restrict__ bias,
    float* __restrict__ Cf, unsigned short* __restrict__ Ch, unsigned short* __restrict__ Cl,
    int M, int K)
{
    __shared__ unsigned short ldsA_h[128 * 32], ldsA_l[128 * 32];
    __shared__ unsigned short ldsB_h[128 * 32], ldsB_l[128 * 32];

    const int tid  = threadIdx.x;
    const int wid  = tid >> 6, lane = tid & 63;
    const int wr   = wid >> 1, wc = wid & 1;
    const int lrow = lane & 15, lk = lane >> 4;
    const int row0 = blockIdx.x * 128, col0 = blockIdx.y * 128;

    f4 acc[4][4] = {};

    for (int k0 = 0; k0 < K; k0 += 32) {
        __syncthreads();   // previous compute's LDS reads done

        // ---- stage B tiles (B^T rows col0..col0+127, 32 k) via global_load_lds
#pragma unroll
        for (int i = 0; i < 2; i++) {
            const int s = wid * 128 + i * 64 + lane;   // slot 0..511
            const int r = s >> 2, g = s & 3;
            const size_t goff = (size_t)(col0 + r) * K + k0 + g * 8;
            const int lbase = (wid * 128 + i * 64) * 8;   // wave-uniform
            gl16(BTh + goff, ldsB_h + lbase);
            gl16(BTl + goff, ldsB_l + lbase);
        }
        // ---- stage A tiles
        if constexpr (!AF32) {
#pragma unroll
            for (int i = 0; i < 2; i++) {
                const int s = wid * 128 + i * 64 + lane;
                const int r = s >> 2, g = s & 3;
                int grow = row0 + r; if (grow >= M) grow = M - 1;   // clamp: no pad rows
                const size_t goff = (size_t)grow * K + k0 + g * 8;
                const int lbase = (wid * 128 + i * 64) * 8;
                gl16(Ah + goff, ldsA_h + lbase);
                gl16(Al + goff, ldsA_l + lbase);
            }
        } else {
            // reg-stage fp32 A, split hi/lo into LDS
#pragma unroll
            for (int q = 0; q < 4; q++) {
                const int ch = tid * 4 + q;            // 0..1023
                const int r = ch >> 3, c4 = ch & 7;
                const float4 v = *(const float4*)(Af + (size_t)(row0 + r) * K + k0 + c4 * 4);
                unsigned short h0, l0, h1, l1, h2, l2, h3, l3;
                split_bf(v.x, h0, l0); split_bf(v.y, h1, l1);
                split_bf(v.z, h2, l2); split_bf(v.w, h3, l3);
                *(ushort4*)&ldsA_h[r * 32 + c4 * 4] = make_ushort4(h0, h1, h2, h3);
                *(ushort4*)&ldsA_l[r * 32 + c4 * 4] = make_ushort4(l0, l1, l2, l3);
            }
        }
        __syncthreads();   // drains vmcnt + lgkmcnt

        // ---- compute: fragment reads + 48 MFMA
        const int aoff = (wr * 64 + lrow) * 32 + lk * 8;
        const int boff = (wc * 64 + lrow) * 32 + lk * 8;
        b8 a_h[4], b_h[4], tmp[4];
#pragma unroll
        for (int m = 0; m < 4; m++) a_h[m] = *(const b8*)&ldsA_h[aoff + m * 512];
#pragma unroll
        for (int n = 0; n < 4; n++) b_h[n] = *(const b8*)&ldsB_h[boff + n * 512];
#pragma unroll
        for (int m = 0; m < 4; m++)
#pragma unroll
            for (int n = 0; n < 4; n++)
                acc[m][n] = mfma16(a_h[m], b_h[n], acc[m][n]);
        // A_lo x B_hi
#pragma unroll
        for (int m = 0; m < 4; m++) tmp[m] = *(const b8*)&ldsA_l[aoff + m * 512];
#pragma unroll
        for (int m = 0; m < 4; m++)
#pragma unroll
            for (int n = 0; n < 4; n++)
                acc[m][n] = mfma16(tmp[m], b_h[n], acc[m][n]);
        // A_hi x B_lo
#pragma unroll
        for (int n = 0; n < 4; n++) tmp[n] = *(const b8*)&ldsB_l[boff + n * 512];
#pragma unroll
        for (int m = 0; m < 4; m++)
#pragma unroll
            for (int n = 0; n < 4; n++)
                acc[m][n] = mfma16(a_h[m], tmp[n], acc[m][n]);
    }

    // ---- epilogue. D frag: row = 4*lk + reg, col = lrow (m89-verified layout)
    const int gcolbase = col0 + wc * 64;
    float biasn[4];
#pragma unroll
    for (int n = 0; n < 4; n++) biasn[n] = bias[gcolbase + n * 16 + lrow];

#pragma unroll
    for (int m = 0; m < 4; m++) {
#pragma unroll
        for (int r = 0; r < 4; r++) {
            const int grow = row0 + wr * 64 + m * 16 + lk * 4 + r;
            if (grow < M) {
#pragma unroll
                for (int n = 0; n < 4; n++) {
                    float v = acc[m][n][r] + biasn[n];
                    const int gcol = gcolbase + n * 16 + lrow;
                    if constexpr (MODE == 0) {
                        Cf[(size_t)grow * HID + gcol] = v;
                    } else {
                        if constexpr (MODE == 1) v = gelu_f(v);
                        const int orow = (MODE == 2) ? (grow + grow / SEQL + 1) : grow;
                        unsigned short h, l; split_bf(v, h, l);
                        Ch[(size_t)orow * HID + gcol] = h;
                        Cl[(size_t)orow * HID + gcol] = l;
                    }
                }
            }
        }
    }
}

// ---------------------------------------------------------------------------
// x[b*577 + 0] = pooled[b]  (hi/lo split)
// ---------------------------------------------------------------------------
__global__ void build_x_pooled(const float* __restrict__ pooled,
                               unsigned short* __restrict__ xH,
                               unsigned short* __restrict__ xL)
{
    const int b = blockIdx.x;
    const int t = threadIdx.x;   // 512 threads
    float v = pooled[b * HID + t];
    unsigned short h, l; split_bf(v, h, l);
    xH[(size_t)(b * NNODE) * HID + t] = h;
    xL[(size_t)(b * NNODE) * HID + t] = l;
}

// ---------------------------------------------------------------------------
// GAT combine, dst j >= 1: softmax over {src=0, src=j}. One block per node.
// ---------------------------------------------------------------------------
template<int HEADS, bool GELU, bool OSPLIT>
__global__ __launch_bounds__(256) void gat_edge_k(
    const float* __restrict__ xl, const float* __restrict__ xr,
    const float* __restrict__ att, const float* __restrict__ bias,
    float* __restrict__ outF, unsigned short* __restrict__ outH,
    unsigned short* __restrict__ outL)
{
    const int b = blockIdx.x / SEQL;
    const int j = blockIdx.x % SEQL;
    const size_t row0 = (size_t)(b * NNODE) * HID;
    const size_t rowj = (size_t)(b * NNODE + 1 + j) * HID;
    const int t = threadIdx.x;
    const int c = 2 * t;

    const float2 xl0  = *(const float2*)(xl + row0 + c);
    const float2 xljv = *(const float2*)(xl + rowj + c);
    const float2 xrjv = *(const float2*)(xr + rowj + c);
    const float2 attc = *(const float2*)(att + c);

    float e0 = attc.x * lrelu(xl0.x + xrjv.x) + attc.y * lrelu(xl0.y + xrjv.y);
    float e1 = attc.x * lrelu(xljv.x + xrjv.x) + attc.y * lrelu(xljv.y + xrjv.y);

#pragma unroll
    for (int off = 32; off; off >>= 1) {
        e0 += __shfl_down(e0, off, 64);
        e1 += __shfl_down(e1, off, 64);
    }
    __shared__ float s0[4], s1[4];
    const int w = t >> 6, lane = t & 63;
    if (lane == 0) { s0[w] = e0; s1[w] = e1; }
    __syncthreads();

    float E0, E1;
    if (HEADS == 4) { E0 = s0[w]; E1 = s1[w]; }
    else            { E0 = s0[0] + s0[1] + s0[2] + s0[3];
                      E1 = s1[0] + s1[1] + s1[2] + s1[3]; }

    const float m  = fmaxf(E0, E1);
    const float p0 = expf(E0 - m);
    const float p1 = expf(E1 - m);
    const float inv = 1.0f / (p0 + p1 + 1e-16f);
    const float a0 = p0 * inv, a1 = p1 * inv;

    float ox = a0 * xl0.x + a1 * xljv.x + bias[c + 0];
    float oy = a0 * xl0.y + a1 * xljv.y + bias[c + 1];
    if (GELU) { ox = gelu_f(ox); oy = gelu_f(oy); }
    if constexpr (OSPLIT) {
        unsigned short h0, l0, h1, l1;
        split_bf(ox, h0, l0); split_bf(oy, h1, l1);
        *(ushort2*)&outH[rowj + c] = make_ushort2(h0, h1);
        *(ushort2*)&outL[rowj + c] = make_ushort2(l0, l1);
    } else {
        *(float2*)(outF + rowj + c) = make_float2(ox, oy);
    }
}

// ---------------------------------------------------------------------------
// GAT combine, dst node 0: softmax over all 577 sources.
// One block per (batch, head).
// ---------------------------------------------------------------------------
template<int HEADS, bool GELU, bool OSPLIT>
__global__ __launch_bounds__(256) void gat_node0_k(
    const float* __restrict__ xl, const float* __restrict__ xr,
    const float* __restrict__ att, const float* __restrict__ bias,
    float* __restrict__ outF, unsigned short* __restrict__ outH,
    unsigned short* __restrict__ outL)
{
    constexpr int CH = HID / HEADS;
    const int b = blockIdx.x;
    const int h = blockIdx.y;
    const int t = threadIdx.x;
    const size_t base = (size_t)(b * NNODE) * HID;

    __shared__ float xr0s[CH];
    __shared__ float es[NNODE];
    __shared__ float red[256];

    const float* atth = att + h * CH;
    for (int c = t; c < CH; c += 256) xr0s[c] = xr[base + h * CH + c];
    __syncthreads();

    for (int s = t; s < NNODE; s += 256) {
        const float* xls = xl + base + (size_t)s * HID + h * CH;
        float e = 0.0f;
        for (int c = 0; c < CH; c += 4) {
            float4 v = *(const float4*)(xls + c);
            float4 a = *(const float4*)(atth + c);
            e = fmaf(a.x, lrelu(v.x + xr0s[c + 0]), e);
            e = fmaf(a.y, lrelu(v.y + xr0s[c + 1]), e);
            e = fmaf(a.z, lrelu(v.z + xr0s[c + 2]), e);
            e = fmaf(a.w, lrelu(v.w + xr0s[c + 3]), e);
        }
        es[s] = e;
    }
    __syncthreads();

    float m = -INFINITY;
    for (int s = t; s < NNODE; s += 256) m = fmaxf(m, es[s]);
    red[t] = m; __syncthreads();
    for (int off = 128; off; off >>= 1) {
        if (t < off) red[t] = fmaxf(red[t], red[t + off]);
        __syncthreads();
    }
    m = red[0];
    __syncthreads();

    float sum = 0.0f;
    for (int s = t; s < NNODE; s += 256) {
        float p = expf(es[s] - m);
        es[s] = p;
        sum += p;
    }
    red[t] = sum; __syncthreads();
    for (int off = 128; off; off >>= 1) {
        if (t < off) red[t] += red[t + off];
        __syncthreads();
    }
    const float invS = 1.0f / (red[0] + 1e-16f);

    for (int c = t; c < CH; c += 256) {
        float acc = 0.0f;
        for (int s = 0; s < NNODE; s++)
            acc = fmaf(es[s], xl[base + (size_t)s * HID + h * CH + c], acc);
        float o = acc * invS + bias[h * CH + c];
        if (GELU) o = gelu_f(o);
        if constexpr (OSPLIT) {
            unsigned short hh, ll; split_bf(o, hh, ll);
            outH[base + h * CH + c] = hh;
            outL[base + h * CH + c] = ll;
        } else {
            outF[base + h * CH + c] = o;
        }
    }
}

// ---------------------------------------------------------------------------
__global__ __launch_bounds__(256) void mean_k(const float* __restrict__ h2,
                                              float* __restrict__ out)
{
    const int b = blockIdx.x;
    const int c = blockIdx.y * 256 + threadIdx.x;
    const float* p = h2 + (size_t)(b * NNODE) * HID + c;
    float s = 0.0f;
    for (int i = 0; i < NNODE; i++) s += p[(size_t)i * HID];
    out[(size_t)BSZ * HID + b * HID + c] = s * (1.0f / NNODE);
}

__global__ __launch_bounds__(256) void head_k(
    const float* __restrict__ h2, const float* __restrict__ linw,
    const float* __restrict__ linb, const float* __restrict__ pooled,
    float* __restrict__ out)
{
    const int b = blockIdx.x;
    const int col = blockIdx.y * 256 + threadIdx.x;
    __shared__ float cls[HID];
    for (int k = threadIdx.x; k < HID; k += 256)
        cls[k] = h2[(size_t)(b * NNODE) * HID + k];
    __syncthreads();
    float acc = 0.0f;
    for (int k = 0; k < HID; k++)
        acc = fmaf(cls[k], linw[(size_t)k * HID + col], acc);
    out[b * HID + col] = acc + linb[col] + pooled[b * HID + col];
}

// ---------------------------------------------------------------------------
extern "C" void kernel_launch(void* const* d_in, const int* in_sizes, int n_in,
                              void* d_out, int out_size, void* d_ws, size_t ws_size,
                              hipStream_t stream)
{
    const float* hs     = (const float*)d_in[0];
    const float* pooled = (const float*)d_in[1];
    const float* pw1  = (const float*)d_in[2];  const float* pb1   = (const float*)d_in[3];
    const float* pw2  = (const float*)d_in[4];  const float* pb2   = (const float*)d_in[5];
    const float* wl1  = (const float*)d_in[6];  const float* bl1   = (const float*)d_in[7];
    const float* wr1  = (const float*)d_in[8];  const float* br1   = (const float*)d_in[9];
    const float* att1 = (const float*)d_in[10]; const float* bias1 = (const float*)d_in[11];
    const float* wl2  = (const float*)d_in[12]; const float* bl2   = (const float*)d_in[13];
    const float* wr2  = (const float*)d_in[14]; const float* br2   = (const float*)d_in[15];
    const float* att2 = (const float*)d_in[16]; const float* bias2 = (const float*)d_in[17];
    const float* linw = (const float*)d_in[18]; const float* linb  = (const float*)d_in[19];
    float* out = (float*)d_out;

    // ---- workspace arena: 3 rotating 72 MiB regions + weight region (~231 MB)
    char* ws = (char*)d_ws;
    const size_t RSZ = 75637760;   // >= max(f32 slot 75636736, bf16 pair 75628544)
    char* R0 = ws;                 // hH/hL -> xr1 -> xr2
    char* R1 = ws + RSZ;           // xH/xL -> h1H/h1L -> h2
    char* R2 = ws + 2 * RSZ;       // pw1T/pw2T -> xl1 -> xl2
    unsigned short* WT = (unsigned short*)(ws + 3 * RSZ);  // 8 x 512*512 bf16

    unsigned short* hH = (unsigned short*)R0;
    unsigned short* hL = (unsigned short*)(R0 + (size_t)MROWS * HID * 2);
    unsigned short* xH = (unsigned short*)R1;
    unsigned short* xL = (unsigned short*)(R1 + (size_t)NUM_NODES * HID * 2);
    unsigned short* h1H = xH;          // reuse R1 after x is consumed
    unsigned short* h1L = xL;
    float* xl_f = (float*)R2;
    float* xr_f = (float*)R0;
    float* h2   = (float*)R1;

    unsigned short* pw1T_h = (unsigned short*)R2;
    unsigned short* pw1T_l = pw1T_h + (size_t)HID * FTIN;
    unsigned short* pw2T_h = pw1T_l + (size_t)HID * FTIN;
    unsigned short* pw2T_l = pw2T_h + (size_t)HID * HID;
    const size_t WSTEP = (size_t)HID * HID;   // 262144

    const dim3 blk(256);
    const dim3 g1(MROWS / 128, 4);                  // 288 x 4
    const dim3 g2((NUM_NODES + 127) / 128, 4);      // 289 x 4

    // 0) weight transpose + hi/lo split
    transpose_split_k<<<dim3(FTIN / 64, HID / 64), blk, 0, stream>>>(pw1, pw1T_h, pw1T_l, FTIN, HID);
    transpose_split_k<<<dim3(8, 8), blk, 0, stream>>>(pw2, pw2T_h, pw2T_l, HID, HID);
    transpose_split_k<<<dim3(8, 8), blk, 0, stream>>>(wl1, WT + 0 * WSTEP, WT + 1 * WSTEP, HID, HID);
    transpose_split_k<<<dim3(8, 8), blk, 0, stream>>>(wr1, WT + 2 * WSTEP, WT + 3 * WSTEP, HID, HID);
    transpose_split_k<<<dim3(8, 8), blk, 0, stream>>>(wl2, WT + 4 * WSTEP, WT + 5 * WSTEP, HID, HID);
    transpose_split_k<<<dim3(8, 8), blk, 0, stream>>>(wr2, WT + 6 * WSTEP, WT + 7 * WSTEP, HID, HID);

    // 1) h = gelu(hs @ pw1 + pb1)            -> hH/hL (R0)
    bgemm<1, true><<<g1, blk, 0, stream>>>(nullptr, nullptr, hs, pw1T_h, pw1T_l, pb1,
                                           nullptr, hH, hL, MROWS, FTIN);
    // 2) x(seq rows) = h @ pw2 + pb2 (remap) -> xH/xL (R1); node-0 rows = pooled
    bgemm<2, false><<<g1, blk, 0, stream>>>(hH, hL, nullptr, pw2T_h, pw2T_l, pb2,
                                            nullptr, xH, xL, MROWS, HID);
    build_x_pooled<<<dim3(BSZ), dim3(512), 0, stream>>>(pooled, xH, xL);
    // 3) GAT1 projections: xl1 (R2), xr1 (R0)
    bgemm<0, false><<<g2, blk, 0, stream>>>(xH, xL, nullptr, WT + 0 * WSTEP, WT + 1 * WSTEP, bl1,
                                            xl_f, nullptr, nullptr, NUM_NODES, HID);
    bgemm<0, false><<<g2, blk, 0, stream>>>(xH, xL, nullptr, WT + 2 * WSTEP, WT + 3 * WSTEP, br1,
                                            xr_f, nullptr, nullptr, NUM_NODES, HID);
    // 4) GAT1 combine (+bias, gelu) -> h1H/h1L (R1)
    gat_edge_k<4, true, true><<<dim3(MROWS), blk, 0, stream>>>(xl_f, xr_f, att1, bias1,
                                                               nullptr, h1H, h1L);
    gat_node0_k<4, true, true><<<dim3(BSZ, 4), blk, 0, stream>>>(xl_f, xr_f, att1, bias1,
                                                                 nullptr, h1H, h1L);
    // 5) GAT2 projections: xl2 (R2), xr2 (R0)
    bgemm<0, false><<<g2, blk, 0, stream>>>(h1H, h1L, nullptr, WT + 4 * WSTEP, WT + 5 * WSTEP, bl2,
                                            xl_f, nullptr, nullptr, NUM_NODES, HID);
    bgemm<0, false><<<g2, blk, 0, stream>>>(h1H, h1L, nullptr, WT + 6 * WSTEP, WT + 7 * WSTEP, br2,
                                            xr_f, nullptr, nullptr, NUM_NODES, HID);
    // 6) GAT2 combine (+bias) -> h2 f32 (R1)
    gat_edge_k<1, false, false><<<dim3(MROWS), blk, 0, stream>>>(xl_f, xr_f, att2, bias2,
                                                                 h2, nullptr, nullptr);
    gat_node0_k<1, false, false><<<dim3(BSZ, 1), blk, 0, stream>>>(xl_f, xr_f, att2, bias2,
                                                                   h2, nullptr, nullptr);
    // 7) outputs
    head_k<<<dim3(BSZ, 2), blk, 0, stream>>>(h2, linw, linb, pooled, out);
    mean_k<<<dim3(BSZ, 2), blk, 0, stream>>>(h2, out);
}

// Round 3
// 1027.562 us; speedup vs baseline: 1.9662x; 1.0547x over previous
//
#include <hip/hip_runtime.h>
#include <hip/hip_bf16.h>
#include <math.h>

// Problem constants (fixed by the reference)
constexpr int BSZ       = 64;
constexpr int SEQL      = 576;
constexpr int FTIN      = 768;
constexpr int HID       = 512;
constexpr int NNODE     = SEQL + 1;          // 577
constexpr int NUM_NODES = BSZ * NNODE;       // 36928
constexpr int MROWS     = BSZ * SEQL;        // 36864

using b8 = __attribute__((ext_vector_type(8))) __bf16;
using f4 = __attribute__((ext_vector_type(4))) float;

__device__ __forceinline__ float gelu_f(float x) {
    float x3 = x * x * x;
    return 0.5f * x * (1.0f + tanhf(0.7978845608028654f * (x + 0.044715f * x3)));
}
__device__ __forceinline__ float lrelu(float x) {
    return x > 0.0f ? x : 0.2f * x;
}
__device__ __forceinline__ unsigned short f2bf(float v) {
    __hip_bfloat16 b = __float2bfloat16(v);   // RNE
    return __builtin_bit_cast(unsigned short, b);
}
__device__ __forceinline__ float bf2f(unsigned short u) {
    return __bfloat162float(__builtin_bit_cast(__hip_bfloat16, u));
}
__device__ __forceinline__ void split_bf(float v, unsigned short& h, unsigned short& l) {
    h = f2bf(v);
    l = f2bf(v - bf2f(h));
}
__device__ __forceinline__ void gl16(const void* g, void* l) {
    __builtin_amdgcn_global_load_lds(
        (const __attribute__((address_space(1))) unsigned int*)g,
        (__attribute__((address_space(3))) unsigned int*)l, 16, 0, 0);
}
__device__ __forceinline__ f4 mfma16(b8 a, b8 b, f4 c) {
    return __builtin_amdgcn_mfma_f32_16x16x32_bf16(a, b, c, 0, 0, 0);
}

// ---------------------------------------------------------------------------
// Weight prep: W fp32 [K x N] -> W^T hi/lo bf16 [N x K]
// ---------------------------------------------------------------------------
__global__ __launch_bounds__(256) void transpose_split_k(
    const float* __restrict__ W, unsigned short* __restrict__ Th,
    unsigned short* __restrict__ Tl, int K, int N)
{
    __shared__ float t[64][65];
    const int kb = blockIdx.x * 64, nb = blockIdx.y * 64;
    for (int i = threadIdx.x; i < 64 * 64; i += 256) {
        int r = i >> 6, c = i & 63;
        t[r][c] = W[(size_t)(kb + r) * N + nb + c];
    }
    __syncthreads();
    for (int i = threadIdx.x; i < 64 * 64; i += 256) {
        int r = i >> 6, c = i & 63;          // r: n index, c: k index
        float v = t[c][r];
        unsigned short h, l; split_bf(v, h, l);
        Th[(size_t)(nb + r) * K + kb + c] = h;
        Tl[(size_t)(nb + r) * K + kb + c] = l;
    }
}

// ---------------------------------------------------------------------------
// MFMA GEMM, hi/lo bf16 split (3-product). Swizzled LDS:
//   tile rows of 32 shorts = 4x 16B slots; phys_slot = log_slot ^ (row & 3).
//   global_load_lds dest stays LINEAR; the involution is applied on the
//   global source chunk index (stage) and on the ds_read address (compute)
//   — both-sides rule (m104/m231).
// C[M x 512] = A[M x K] @ B[K x 512] + bias, then per MODE:
//   MODE 0: write fp32 | MODE 1: gelu -> hi/lo bf16 | MODE 2: remap -> hi/lo
// ---------------------------------------------------------------------------
template<int MODE, bool AF32>
__global__ __launch_bounds__(256) void bgemm(
    const unsigned short* __restrict__ Ah, const unsigned short* __restrict__ Al,
    const float* __restrict__ Af,
    const unsigned short* __restrict__ BTh, const unsigned short* __restrict__ BTl,
    const float* __restrict__ bias,
    float* __restrict__ Cf, unsigned short* __restrict__ Ch, unsigned short* __restrict__ Cl,
    int M, int K)
{
    __shared__ unsigned short ldsA_h[128 * 32], ldsA_l[128 * 32];
    __shared__ unsigned short ldsB_h[128 * 32], ldsB_l[128 * 32];

    const int tid  = threadIdx.x;
    const int wid  = tid >> 6, lane = tid & 63;
    const int wr   = wid >> 1, wc = wid & 1;
    const int lrow = lane & 15, lk = lane >> 4;
    const int row0 = blockIdx.x * 128, col0 = blockIdx.y * 128;

    f4 acc[4][4] = {};

    // swizzled fragment read offsets (shorts): row*32 + (lk ^ (row&3))*8
    const int sw   = lrow & 3;
    const int aoff = (wr * 64 + lrow) * 32 + ((lk ^ sw)) * 8;
    const int boff = (wc * 64 + lrow) * 32 + ((lk ^ sw)) * 8;

    for (int k0 = 0; k0 < K; k0 += 32) {
        __syncthreads();   // previous compute's LDS reads done

        // ---- stage B tiles via global_load_lds (linear dest, swizzled source)
#pragma unroll
        for (int i = 0; i < 2; i++) {
            const int s = wid * 128 + i * 64 + lane;     // slot 0..511
            const int r = s >> 2;
            const int g = (s & 3) ^ (r & 3);             // pre-swizzled chunk
            const size_t goff = (size_t)(col0 + r) * K + k0 + g * 8;
            const int lbase = (wid * 128 + i * 64) * 8;  // wave-uniform
            gl16(BTh + goff, ldsB_h + lbase);
            gl16(BTl + goff, ldsB_l + lbase);
        }
        // ---- stage A tiles
        if constexpr (!AF32) {
#pragma unroll
            for (int i = 0; i < 2; i++) {
                const int s = wid * 128 + i * 64 + lane;
                const int r = s >> 2;
                const int g = (s & 3) ^ (r & 3);
                int grow = row0 + r; if (grow >= M) grow = M - 1;   // clamp
                const size_t goff = (size_t)grow * K + k0 + g * 8;
                const int lbase = (wid * 128 + i * 64) * 8;
                gl16(Ah + goff, ldsA_h + lbase);
                gl16(Al + goff, ldsA_l + lbase);
            }
        } else {
            // reg-stage fp32 A, split hi/lo into LDS (swizzled ds_write)
#pragma unroll
            for (int q = 0; q < 4; q++) {
                const int ch = tid * 4 + q;            // 0..1023
                const int r = ch >> 3, c4 = ch & 7;
                const float4 v = *(const float4*)(Af + (size_t)(row0 + r) * K + k0 + c4 * 4);
                unsigned short h0, l0, h1, l1, h2, l2, h3, l3;
                split_bf(v.x, h0, l0); split_bf(v.y, h1, l1);
                split_bf(v.z, h2, l2); split_bf(v.w, h3, l3);
                const int slot = (c4 >> 1) ^ (r & 3);
                const int off  = r * 32 + slot * 8 + (c4 & 1) * 4;
                *(ushort4*)&ldsA_h[off] = make_ushort4(h0, h1, h2, h3);
                *(ushort4*)&ldsA_l[off] = make_ushort4(l0, l1, l2, l3);
            }
        }
        __syncthreads();   // drains vmcnt + lgkmcnt

        // ---- compute: fragment reads + 48 MFMA
        b8 a_h[4], b_h[4], tmp[4];
#pragma unroll
        for (int m = 0; m < 4; m++) a_h[m] = *(const b8*)&ldsA_h[aoff + m * 512];
#pragma unroll
        for (int n = 0; n < 4; n++) b_h[n] = *(const b8*)&ldsB_h[boff + n * 512];
#pragma unroll
        for (int m = 0; m < 4; m++)
#pragma unroll
            for (int n = 0; n < 4; n++)
                acc[m][n] = mfma16(a_h[m], b_h[n], acc[m][n]);
        // A_lo x B_hi
#pragma unroll
        for (int m = 0; m < 4; m++) tmp[m] = *(const b8*)&ldsA_l[aoff + m * 512];
#pragma unroll
        for (int m = 0; m < 4; m++)
#pragma unroll
            for (int n = 0; n < 4; n++)
                acc[m][n] = mfma16(tmp[m], b_h[n], acc[m][n]);
        // A_hi x B_lo
#pragma unroll
        for (int n = 0; n < 4; n++) tmp[n] = *(const b8*)&ldsB_l[boff + n * 512];
#pragma unroll
        for (int m = 0; m < 4; m++)
#pragma unroll
            for (int n = 0; n < 4; n++)
                acc[m][n] = mfma16(a_h[m], tmp[n], acc[m][n]);
    }

    // ---- epilogue. D frag: row = 4*lk + reg, col = lrow (m89 layout)
    const int gcolbase = col0 + wc * 64;
    float biasn[4];
#pragma unroll
    for (int n = 0; n < 4; n++) biasn[n] = bias[gcolbase + n * 16 + lrow];

#pragma unroll
    for (int m = 0; m < 4; m++) {
#pragma unroll
        for (int r = 0; r < 4; r++) {
            const int grow = row0 + wr * 64 + m * 16 + lk * 4 + r;
            if (grow < M) {
#pragma unroll
                for (int n = 0; n < 4; n++) {
                    float v = acc[m][n][r] + biasn[n];
                    const int gcol = gcolbase + n * 16 + lrow;
                    if constexpr (MODE == 0) {
                        Cf[(size_t)grow * HID + gcol] = v;
                    } else {
                        if constexpr (MODE == 1) v = gelu_f(v);
                        const int orow = (MODE == 2) ? (grow + grow / SEQL + 1) : grow;
                        unsigned short h, l; split_bf(v, h, l);
                        Ch[(size_t)orow * HID + gcol] = h;
                        Cl[(size_t)orow * HID + gcol] = l;
                    }
                }
            }
        }
    }
}

// ---------------------------------------------------------------------------
// x[b*577 + 0] = pooled[b]  (hi/lo split)
// ---------------------------------------------------------------------------
__global__ void build_x_pooled(const float* __restrict__ pooled,
                               unsigned short* __restrict__ xH,
                               unsigned short* __restrict__ xL)
{
    const int b = blockIdx.x;
    const int t = threadIdx.x;   // 512 threads
    float v = pooled[b * HID + t];
    unsigned short h, l; split_bf(v, h, l);
    xH[(size_t)(b * NNODE) * HID + t] = h;
    xL[(size_t)(b * NNODE) * HID + t] = l;
}

// ---------------------------------------------------------------------------
// GAT combine, dst j >= 1: softmax over {src=0, src=j}. One block per node.
// ---------------------------------------------------------------------------
template<int HEADS, bool GELU, bool OSPLIT>
__global__ __launch_bounds__(256) void gat_edge_k(
    const float* __restrict__ xl, const float* __restrict__ xr,
    const float* __restrict__ att, const float* __restrict__ bias,
    float* __restrict__ outF, unsigned short* __restrict__ outH,
    unsigned short* __restrict__ outL)
{
    const int b = blockIdx.x / SEQL;
    const int j = blockIdx.x % SEQL;
    const size_t row0 = (size_t)(b * NNODE) * HID;
    const size_t rowj = (size_t)(b * NNODE + 1 + j) * HID;
    const int t = threadIdx.x;
    const int c = 2 * t;

    const float2 xl0  = *(const float2*)(xl + row0 + c);
    const float2 xljv = *(const float2*)(xl + rowj + c);
    const float2 xrjv = *(const float2*)(xr + rowj + c);
    const float2 attc = *(const float2*)(att + c);

    float e0 = attc.x * lrelu(xl0.x + xrjv.x) + attc.y * lrelu(xl0.y + xrjv.y);
    float e1 = attc.x * lrelu(xljv.x + xrjv.x) + attc.y * lrelu(xljv.y + xrjv.y);

#pragma unroll
    for (int off = 32; off; off >>= 1) {
        e0 += __shfl_down(e0, off, 64);
        e1 += __shfl_down(e1, off, 64);
    }
    __shared__ float s0[4], s1[4];
    const int w = t >> 6, lane = t & 63;
    if (lane == 0) { s0[w] = e0; s1[w] = e1; }
    __syncthreads();

    float E0, E1;
    if (HEADS == 4) { E0 = s0[w]; E1 = s1[w]; }
    else            { E0 = s0[0] + s0[1] + s0[2] + s0[3];
                      E1 = s1[0] + s1[1] + s1[2] + s1[3]; }

    const float m  = fmaxf(E0, E1);
    const float p0 = expf(E0 - m);
    const float p1 = expf(E1 - m);
    const float inv = 1.0f / (p0 + p1 + 1e-16f);
    const float a0 = p0 * inv, a1 = p1 * inv;

    float ox = a0 * xl0.x + a1 * xljv.x + bias[c + 0];
    float oy = a0 * xl0.y + a1 * xljv.y + bias[c + 1];
    if (GELU) { ox = gelu_f(ox); oy = gelu_f(oy); }
    if constexpr (OSPLIT) {
        unsigned short h0, l0, h1, l1;
        split_bf(ox, h0, l0); split_bf(oy, h1, l1);
        *(ushort2*)&outH[rowj + c] = make_ushort2(h0, h1);
        *(ushort2*)&outL[rowj + c] = make_ushort2(l0, l1);
    } else {
        *(float2*)(outF + rowj + c) = make_float2(ox, oy);
    }
}

// ---------------------------------------------------------------------------
// GAT combine, dst node 0: softmax over all 577 sources.
// One block per (batch, head).
// ---------------------------------------------------------------------------
template<int HEADS, bool GELU, bool OSPLIT>
__global__ __launch_bounds__(256) void gat_node0_k(
    const float* __restrict__ xl, const float* __restrict__ xr,
    const float* __restrict__ att, const float* __restrict__ bias,
    float* __restrict__ outF, unsigned short* __restrict__ outH,
    unsigned short* __restrict__ outL)
{
    constexpr int CH = HID / HEADS;
    const int b = blockIdx.x;
    const int h = blockIdx.y;
    const int t = threadIdx.x;
    const size_t base = (size_t)(b * NNODE) * HID;

    __shared__ float xr0s[CH];
    __shared__ float es[NNODE];
    __shared__ float red[256];

    const float* atth = att + h * CH;
    for (int c = t; c < CH; c += 256) xr0s[c] = xr[base + h * CH + c];
    __syncthreads();

    for (int s = t; s < NNODE; s += 256) {
        const float* xls = xl + base + (size_t)s * HID + h * CH;
        float e = 0.0f;
        for (int c = 0; c < CH; c += 4) {
            float4 v = *(const float4*)(xls + c);
            float4 a = *(const float4*)(atth + c);
            e = fmaf(a.x, lrelu(v.x + xr0s[c + 0]), e);
            e = fmaf(a.y, lrelu(v.y + xr0s[c + 1]), e);
            e = fmaf(a.z, lrelu(v.z + xr0s[c + 2]), e);
            e = fmaf(a.w, lrelu(v.w + xr0s[c + 3]), e);
        }
        es[s] = e;
    }
    __syncthreads();

    float m = -INFINITY;
    for (int s = t; s < NNODE; s += 256) m = fmaxf(m, es[s]);
    red[t] = m; __syncthreads();
    for (int off = 128; off; off >>= 1) {
        if (t < off) red[t] = fmaxf(red[t], red[t + off]);
        __syncthreads();
    }
    m = red[0];
    __syncthreads();

    float sum = 0.0f;
    for (int s = t; s < NNODE; s += 256) {
        float p = expf(es[s] - m);
        es[s] = p;
        sum += p;
    }
    red[t] = sum; __syncthreads();
    for (int off = 128; off; off >>= 1) {
        if (t < off) red[t] += red[t + off];
        __syncthreads();
    }
    const float invS = 1.0f / (red[0] + 1e-16f);

    for (int c = t; c < CH; c += 256) {
        float acc = 0.0f;
        for (int s = 0; s < NNODE; s++)
            acc = fmaf(es[s], xl[base + (size_t)s * HID + h * CH + c], acc);
        float o = acc * invS + bias[h * CH + c];
        if (GELU) o = gelu_f(o);
        if constexpr (OSPLIT) {
            unsigned short hh, ll; split_bf(o, hh, ll);
            outH[base + h * CH + c] = hh;
            outL[base + h * CH + c] = ll;
        } else {
            outF[base + h * CH + c] = o;
        }
    }
}

// ---------------------------------------------------------------------------
__global__ __launch_bounds__(256) void mean_k(const float* __restrict__ h2,
                                              float* __restrict__ out)
{
    const int b = blockIdx.x;
    const int c = blockIdx.y * 256 + threadIdx.x;
    const float* p = h2 + (size_t)(b * NNODE) * HID + c;
    float s = 0.0f;
    for (int i = 0; i < NNODE; i++) s += p[(size_t)i * HID];
    out[(size_t)BSZ * HID + b * HID + c] = s * (1.0f / NNODE);
}

__global__ __launch_bounds__(256) void head_k(
    const float* __restrict__ h2, const float* __restrict__ linw,
    const float* __restrict__ linb, const float* __restrict__ pooled,
    float* __restrict__ out)
{
    const int b = blockIdx.x;
    const int col = blockIdx.y * 256 + threadIdx.x;
    __shared__ float cls[HID];
    for (int k = threadIdx.x; k < HID; k += 256)
        cls[k] = h2[(size_t)(b * NNODE) * HID + k];
    __syncthreads();
    float acc = 0.0f;
    for (int k = 0; k < HID; k++)
        acc = fmaf(cls[k], linw[(size_t)k * HID + col], acc);
    out[b * HID + col] = acc + linb[col] + pooled[b * HID + col];
}

// ---------------------------------------------------------------------------
extern "C" void kernel_launch(void* const* d_in, const int* in_sizes, int n_in,
                              void* d_out, int out_size, void* d_ws, size_t ws_size,
                              hipStream_t stream)
{
    const float* hs     = (const float*)d_in[0];
    const float* pooled = (const float*)d_in[1];
    const float* pw1  = (const float*)d_in[2];  const float* pb1   = (const float*)d_in[3];
    const float* pw2  = (const float*)d_in[4];  const float* pb2   = (const float*)d_in[5];
    const float* wl1  = (const float*)d_in[6];  const float* bl1   = (const float*)d_in[7];
    const float* wr1  = (const float*)d_in[8];  const float* br1   = (const float*)d_in[9];
    const float* att1 = (const float*)d_in[10]; const float* bias1 = (const float*)d_in[11];
    const float* wl2  = (const float*)d_in[12]; const float* bl2   = (const float*)d_in[13];
    const float* wr2  = (const float*)d_in[14]; const float* br2   = (const float*)d_in[15];
    const float* att2 = (const float*)d_in[16]; const float* bias2 = (const float*)d_in[17];
    const float* linw = (const float*)d_in[18]; const float* linb  = (const float*)d_in[19];
    float* out = (float*)d_out;

    // ---- workspace arena: 3 rotating 72 MiB regions + weight region (~231 MB)
    char* ws = (char*)d_ws;
    const size_t RSZ = 75637760;
    char* R0 = ws;                 // hH/hL -> xr1 -> xr2
    char* R1 = ws + RSZ;           // xH/xL -> h1H/h1L -> h2
    char* R2 = ws + 2 * RSZ;       // pw1T/pw2T -> xl1 -> xl2
    unsigned short* WT = (unsigned short*)(ws + 3 * RSZ);  // 8 x 512*512 bf16

    unsigned short* hH = (unsigned short*)R0;
    unsigned short* hL = (unsigned short*)(R0 + (size_t)MROWS * HID * 2);
    unsigned short* xH = (unsigned short*)R1;
    unsigned short* xL = (unsigned short*)(R1 + (size_t)NUM_NODES * HID * 2);
    unsigned short* h1H = xH;          // reuse R1 after x is consumed
    unsigned short* h1L = xL;
    float* xl_f = (float*)R2;
    float* xr_f = (float*)R0;
    float* h2   = (float*)R1;

    unsigned short* pw1T_h = (unsigned short*)R2;
    unsigned short* pw1T_l = pw1T_h + (size_t)HID * FTIN;
    unsigned short* pw2T_h = pw1T_l + (size_t)HID * FTIN;
    unsigned short* pw2T_l = pw2T_h + (size_t)HID * HID;
    const size_t WSTEP = (size_t)HID * HID;   // 262144

    const dim3 blk(256);
    const dim3 g1(MROWS / 128, 4);                  // 288 x 4
    const dim3 g2((NUM_NODES + 127) / 128, 4);      // 289 x 4

    // 0) weight transpose + hi/lo split
    transpose_split_k<<<dim3(FTIN / 64, HID / 64), blk, 0, stream>>>(pw1, pw1T_h, pw1T_l, FTIN, HID);
    transpose_split_k<<<dim3(8, 8), blk, 0, stream>>>(pw2, pw2T_h, pw2T_l, HID, HID);
    transpose_split_k<<<dim3(8, 8), blk, 0, stream>>>(wl1, WT + 0 * WSTEP, WT + 1 * WSTEP, HID, HID);
    transpose_split_k<<<dim3(8, 8), blk, 0, stream>>>(wr1, WT + 2 * WSTEP, WT + 3 * WSTEP, HID, HID);
    transpose_split_k<<<dim3(8, 8), blk, 0, stream>>>(wl2, WT + 4 * WSTEP, WT + 5 * WSTEP, HID, HID);
    transpose_split_k<<<dim3(8, 8), blk, 0, stream>>>(wr2, WT + 6 * WSTEP, WT + 7 * WSTEP, HID, HID);

    // 1) h = gelu(hs @ pw1 + pb1)            -> hH/hL (R0)
    bgemm<1, true><<<g1, blk, 0, stream>>>(nullptr, nullptr, hs, pw1T_h, pw1T_l, pb1,
                                           nullptr, hH, hL, MROWS, FTIN);
    // 2) x(seq rows) = h @ pw2 + pb2 (remap) -> xH/xL (R1); node-0 rows = pooled
    bgemm<2, false><<<g1, blk, 0, stream>>>(hH, hL, nullptr, pw2T_h, pw2T_l, pb2,
                                            nullptr, xH, xL, MROWS, HID);
    build_x_pooled<<<dim3(BSZ), dim3(512), 0, stream>>>(pooled, xH, xL);
    // 3) GAT1 projections: xl1 (R2), xr1 (R0)
    bgemm<0, false><<<g2, blk, 0, stream>>>(xH, xL, nullptr, WT + 0 * WSTEP, WT + 1 * WSTEP, bl1,
                                            xl_f, nullptr, nullptr, NUM_NODES, HID);
    bgemm<0, false><<<g2, blk, 0, stream>>>(xH, xL, nullptr, WT + 2 * WSTEP, WT + 3 * WSTEP, br1,
                                            xr_f, nullptr, nullptr, NUM_NODES, HID);
    // 4) GAT1 combine (+bias, gelu) -> h1H/h1L (R1)
    gat_edge_k<4, true, true><<<dim3(MROWS), blk, 0, stream>>>(xl_f, xr_f, att1, bias1,
                                                               nullptr, h1H, h1L);
    gat_node0_k<4, true, true><<<dim3(BSZ, 4), blk, 0, stream>>>(xl_f, xr_f, att1, bias1,
                                                                 nullptr, h1H, h1L);
    // 5) GAT2 projections: xl2 (R2), xr2 (R0)
    bgemm<0, false><<<g2, blk, 0, stream>>>(h1H, h1L, nullptr, WT + 4 * WSTEP, WT + 5 * WSTEP, bl2,
                                            xl_f, nullptr, nullptr, NUM_NODES, HID);
    bgemm<0, false><<<g2, blk, 0, stream>>>(h1H, h1L, nullptr, WT + 6 * WSTEP, WT + 7 * WSTEP, br2,
                                            xr_f, nullptr, nullptr, NUM_NODES, HID);
    // 6) GAT2 combine (+bias) -> h2 f32 (R1)
    gat_edge_k<1, false, false><<<dim3(MROWS), blk, 0, stream>>>(xl_f, xr_f, att2, bias2,
                                                                 h2, nullptr, nullptr);
    gat_node0_k<1, false, false><<<dim3(BSZ, 1), blk, 0, stream>>>(xl_f, xr_f, att2, bias2,
                                                                   h2, nullptr, nullptr);
    // 7) outputs
    head_k<<<dim3(BSZ, 2), blk, 0, stream>>>(h2, linw, linb, pooled, out);
    mean_k<<<dim3(BSZ, 2), blk, 0, stream>>>(h2, out);
}